// Round 4
// baseline (223.506 us; speedup 1.0000x reference)
//
#include <hip/hip_runtime.h>
#include <hip/hip_bf16.h>

typedef __bf16 bf16_t;
typedef __bf16 bf16x4 __attribute__((ext_vector_type(4)));
typedef __bf16 bf16x8 __attribute__((ext_vector_type(8)));
typedef float f32x4 __attribute__((ext_vector_type(4)));

#define ALPHA 8.3f
#define CPAD 72   // bf16 channel stride (144 B, 16B-aligned)
#define NCOL 68   // staged cols: 64 main + 4 halo

// img: [4][64][256][256] f32, depth: [4][1][256][256] f32,
// weight: [64][64][3][3] f32, bias: [1][64] f32, out: [4][64][254][254] f32

// Repack weight -> bf16 A-fragment order [tap(9)][chunk(2)][mblock(4)][lane(64)][j(8)]
__global__ void repack_w(const float* __restrict__ w, bf16_t* __restrict__ w2) {
    int idx = blockIdx.x * 256 + threadIdx.x;  // 0..36863
    if (idx >= 9 * 2 * 4 * 64 * 8) return;
    int j     = idx & 7;
    int lane  = (idx >> 3) & 63;
    int m     = (idx >> 9) & 3;
    int chunk = (idx >> 11) & 1;
    int tap   = idx >> 12;
    int oc = m * 16 + (lane & 15);
    int c  = chunk * 32 + (lane >> 4) * 8 + j;
    int kt = tap / 3, lt = tap % 3;
    w2[idx] = (bf16_t)w[((oc * 64 + c) * 3 + kt) * 3 + lt];
}

// R0-R3 post-mortem: occupancy 36%/17%/35% all give 67/67/86 us -> NOT TLP-bound.
// Shared flaw: __syncthreads() = s_waitcnt vmcnt(0) -> every block drains all
// global loads before compute; phases lockstep; memory and MFMA never overlap.
// R4: software-pipelined row ring with RAW barriers (lgkmcnt(0)+s_barrier only,
// vmem stays in flight across barriers). Block = 4-row strip x 64q x 64oc;
// 1 row/iter; 4-slot LDS ring. Per iter: compute row p || img row p+3 in
// flight -> cvt+write slot -> issue dep(t+1)+img(p+4) -> raw barrier -> stores.
// Data-dep correctness stays with compiler auto-waitcnts (per-use, precise);
// the raw barrier only gives cross-wave LDS visibility.
__global__ __launch_bounds__(256, 2) void depthconv_mfma(
    const float* __restrict__ img, const float* __restrict__ depth,
    const bf16_t* __restrict__ w2, const float* __restrict__ bias,
    float* __restrict__ out)
{
    __shared__ bf16_t lds[4 * NCOL * CPAD];  // 39,168 B -> 4 blocks/CU

    const int tid = threadIdx.x;
    const int blk = blockIdx.x;
    const int strip = blk >> 4;              // 0..63, 4 output rows each
    const int r     = blk & 15;              // (b,qt): 16%8==0 keeps streams on one XCD
    const int b     = r >> 2;
    const int qt    = r & 3;
    const int pbase = (strip == 63) ? 250 : strip * 4;  // rows 250/251 dup-written identically
    const int q0    = (qt == 3) ? 190 : qt * 64;        // q 190/191 dup-written identically
    const int s0    = (qt == 3) ? 188 : q0;
    const int clb0  = q0 - s0;

    const float* imgb = img + (size_t)b * 64 * 65536;
    const float* dep  = depth + (size_t)b * 65536;

    const int wv   = tid >> 6;
    const int lane = tid & 63;
    const int n    = lane & 15;
    const int quad = lane >> 4;
    const int cg   = tid & 15;   // 4-channel group
    const int colg = tid >> 4;   // 0..15 main col group
    const int hch  = wv * 16 + n;        // halo channel (lane<16 active)
    const bool hact = (lane < 16);

    const f32x4 Z = (f32x4){0.f, 0.f, 0.f, 0.f};

// issue 5 vmem/wave: 4 main f32x4 (cg,colg) + 1 halo f32x4 (cols 64..67)
#define LOAD_ROW(rowL, m, h)                                                              \
    do {                                                                                  \
        const float* _s = imgb + (size_t)(cg * 4) * 65536 + (size_t)(rowL) * 256 + s0 + colg * 4; \
        m[0] = *(const f32x4*)_s;                                                         \
        m[1] = *(const f32x4*)(_s + 65536);                                               \
        m[2] = *(const f32x4*)(_s + 2 * 65536);                                           \
        m[3] = *(const f32x4*)(_s + 3 * 65536);                                           \
        if (hact) h = *(const f32x4*)(imgb + (size_t)hch * 65536 + (size_t)(rowL) * 256 + s0 + 64); \
    } while (0)

#define CVT_WRITE(slot, m, h)                                                             \
    do {                                                                                  \
        bf16_t* _d = lds + ((size_t)(slot) * NCOL + colg * 4) * CPAD + cg * 4;            \
        _Pragma("unroll")                                                                 \
        for (int _i = 0; _i < 4; ++_i)                                                    \
            *(bf16x4*)(_d + _i * CPAD) = (bf16x4){(bf16_t)m[0][_i], (bf16_t)m[1][_i],     \
                                                  (bf16_t)m[2][_i], (bf16_t)m[3][_i]};    \
        if (hact) {                                                                       \
            bf16_t* _hd = lds + ((size_t)(slot) * NCOL + 64) * CPAD + hch;                \
            _Pragma("unroll")                                                             \
            for (int _i = 0; _i < 4; ++_i) _hd[_i * CPAD] = (bf16_t)h[_i];                \
        }                                                                                 \
    } while (0)

#define LOAD_DEP(prow)                                                                    \
    do {                                                                                  \
        _Pragma("unroll") for (int _kt = 0; _kt < 3; ++_kt)                               \
        _Pragma("unroll") for (int _lt = 0; _lt < 3; ++_lt)                               \
        _Pragma("unroll") for (int _i = 0; _i < 4; ++_i)                                  \
            dre[_kt][_lt][_i] = dep[(size_t)((prow) + _kt) * 256 + q0 + 16 * _i + n + _lt]; \
    } while (0)

    // ---- prologue: rows pbase..pbase+2 -> slots 0..2; issue dep(0) + img(pbase+3) ----
    f32x4 ma[4]; f32x4 hA = Z;
    f32x4 mb[4]; f32x4 hB = Z;
    LOAD_ROW(pbase + 0, ma, hA);
    LOAD_ROW(pbase + 1, mb, hB);
    CVT_WRITE(0, ma, hA);
    CVT_WRITE(1, mb, hB);
    LOAD_ROW(pbase + 2, ma, hA);
    float dre[3][3][4];
    LOAD_DEP(pbase);
    f32x4 pm[4]; f32x4 ph = Z;
    LOAD_ROW(pbase + 3, pm, ph);
    CVT_WRITE(2, ma, hA);
    asm volatile("s_waitcnt lgkmcnt(0)" ::: "memory");
    __builtin_amdgcn_s_barrier();      // raw: dep+img stay in flight

    const bf16x8* wbase = (const bf16x8*)w2 + (size_t)wv * 64 + lane;
    float bz[4];
#pragma unroll
    for (int r2 = 0; r2 < 4; ++r2) bz[r2] = bias[wv * 16 + quad * 4 + r2];

#pragma unroll
    for (int t = 0; t < 4; ++t) {
        const int p = pbase + t;

        // depth weights for row p (compiler drains the dep loads here)
        float dwv[3][3][4];
#pragma unroll
        for (int i = 0; i < 4; ++i) {
            const float dc = dre[1][1][i];
#pragma unroll
            for (int kt = 0; kt < 3; ++kt)
#pragma unroll
                for (int lt = 0; lt < 3; ++lt)
                    dwv[kt][lt][i] = __expf(-ALPHA * fabsf(dre[kt][lt][i] - dc));
        }

        f32x4 acc[4];
#pragma unroll
        for (int i = 0; i < 4; ++i) acc[i] = Z;

#pragma unroll
        for (int kt = 0; kt < 3; ++kt) {
            const int slot = (t + kt) & 3;   // row pbase+j lives in slot j&3
#pragma unroll
            for (int lt = 0; lt < 3; ++lt) {
                const int tap = kt * 3 + lt;
                const bf16x8 a0 = wbase[(size_t)(tap * 2 + 0) * 256];
                const bf16x8 a1 = wbase[(size_t)(tap * 2 + 1) * 256];
#pragma unroll
                for (int i = 0; i < 4; ++i) {
                    const bf16_t* lp = lds
                        + ((size_t)slot * NCOL + clb0 + 16 * i + n + lt) * CPAD + quad * 8;
                    const bf16x8 bf0 = *(const bf16x8*)lp;
                    const bf16x8 bf1 = *(const bf16x8*)(lp + 32);
                    f32x4 P = __builtin_amdgcn_mfma_f32_16x16x32_bf16(a0, bf0, Z, 0, 0, 0);
                    P = __builtin_amdgcn_mfma_f32_16x16x32_bf16(a1, bf1, P, 0, 0, 0);
                    acc[i] += dwv[kt][lt][i] * P;
                }
            }
        }

        if (t < 3) {
            LOAD_DEP(p + 1);                       // depth for next row (issued first)
            CVT_WRITE((t + 3) & 3, pm, ph);        // img row p+3 arrives; write its slot
            if (t < 2) LOAD_ROW(pbase + t + 4, pm, ph);  // next prefetch (max row 255)
            asm volatile("s_waitcnt lgkmcnt(0)" ::: "memory");
            __builtin_amdgcn_s_barrier();          // raw: new dep/img stay in flight
        }

        // stores after the barrier: overlap next iteration's compute
#pragma unroll
        for (int r2 = 0; r2 < 4; ++r2) {
            const int oc = wv * 16 + quad * 4 + r2;
#pragma unroll
            for (int i = 0; i < 4; ++i)
                out[((size_t)(b * 64 + oc) * 254 + p) * 254 + q0 + 16 * i + n]
                    = acc[i][r2] + bz[r2];
        }
    }
#undef LOAD_ROW
#undef CVT_WRITE
#undef LOAD_DEP
}

extern "C" void kernel_launch(void* const* d_in, const int* in_sizes, int n_in,
                              void* d_out, int out_size, void* d_ws, size_t ws_size,
                              hipStream_t stream) {
    const float* img   = (const float*)d_in[0];
    const float* depth = (const float*)d_in[1];
    const float* w     = (const float*)d_in[2];
    const float* bias  = (const float*)d_in[3];
    bf16_t* w2 = (bf16_t*)d_ws;

    repack_w<<<144, 256, 0, stream>>>(w, w2);
    // 64 strips x 4 b x 4 q-tiles = 1024 blocks, 256 thr (4 waves)
    depthconv_mfma<<<1024, 256, 0, stream>>>(img, depth, w2, bias, (float*)d_out);
}

// Round 6
// 219.132 us; speedup vs baseline: 1.0200x; 1.0200x over previous
//
#include <hip/hip_runtime.h>
#include <hip/hip_bf16.h>

typedef __bf16 bf16_t;
typedef __bf16 bf16x4 __attribute__((ext_vector_type(4)));
typedef __bf16 bf16x8 __attribute__((ext_vector_type(8)));
typedef float f32x4 __attribute__((ext_vector_type(4)));

#define ALPHA 8.3f
#define CPAD 72   // bf16 channel stride (144 B, 16B-aligned, conflict-free reads)
#define NCOL 68   // staged cols (64-q tile + halo + align)
#define NSLOT 6   // LDS row-ring slots

// img: [4][64][256][256] f32, depth: [4][1][256][256] f32,
// weight: [64][64][3][3] f32, bias: [1][64] f32, out: [4][64][254][254] f32

// Repack weight -> bf16 A-fragment order [tap(9)][chunk(2)][mblock(4)][lane(64)][j(8)]
__global__ void repack_w(const float* __restrict__ w, bf16_t* __restrict__ w2) {
    int idx = blockIdx.x * 256 + threadIdx.x;  // 0..36863
    if (idx >= 9 * 2 * 4 * 64 * 8) return;
    int j     = idx & 7;
    int lane  = (idx >> 3) & 63;
    int m     = (idx >> 9) & 3;
    int chunk = (idx >> 11) & 1;
    int tap   = idx >> 12;
    int oc = m * 16 + (lane & 15);
    int c  = chunk * 32 + (lane >> 4) * 8 + j;
    int kt = tap / 3, lt = tap % 3;
    w2[idx] = (bf16_t)w[((oc * 64 + c) * 3 + kt) * 3 + lt];
}

// R0-R4 conclusions: not BW-bound (R2: FETCH 51MB, same 67us), not TLP-bound
// (R3: +50% waves, worse), not per-wave-ILP-bound (R2: neutral). The invariant
// is stage->barrier->compute phase serialization per CU. R4's pipelining spilled
// (FETCH/WRITE +100MB each) because one wave held both phases' state.
// R5 (rerun; previous round died in harness before launch -- HIP error 100 at
// input hipMalloc): producer/consumer WAVE SPECIALIZATION. 512 thr = 4 consumer
// waves (R0's exact compute, ~60 VGPR) + 4 producer waves (R0's exact stage
// loop, ~60 VGPR) -- disjoint register sets, no spill. 6-row LDS ring (58.8KB
// -> 2 blk/CU) over a 4-tile strip: P(s+1) stages 2 new rows while C(s)
// computes. Raw barriers (lgkmcnt only) keep producer loads + consumer stores
// in flight. Ring slots: P writes {2s+4,2s+5}%6 while C reads {2s..2s+3}%6 --
// 6 consecutive rows, all distinct mod 6 -> race-free. Grid 32 strips x 16
// streams = 512 blocks = exactly 2/CU.
__global__ __launch_bounds__(512, 4) void depthconv_mfma(
    const float* __restrict__ img, const float* __restrict__ depth,
    const bf16_t* __restrict__ w2, const float* __restrict__ bias,
    float* __restrict__ out)
{
    __shared__ bf16_t lds[NSLOT * NCOL * CPAD];  // 58,752 B -> 2 blocks/CU

    const int tid   = threadIdx.x;
    const int blk   = blockIdx.x;
    const int strip = blk >> 4;              // 0..31, 4 tiles (8 output rows) each
    const int r     = blk & 15;              // (b,qt) stream; 16%8==0 -> XCD-stable
    const int b     = r >> 2;
    const int qt    = r & 3;
    // strip 31 overlaps strip 30 (ppair 123) -> identical dup writes
    const int prow0 = ((strip == 31) ? 123 : strip * 4) * 2;
    const int q0    = (qt == 3) ? 190 : qt * 64;   // q 190/191 dup-written identically
    const int s0    = (qt == 3) ? 188 : q0;        // staged col start (float4-aligned)
    const int clb0  = q0 - s0;

    const float* imgb = img + (size_t)b * 64 * 65536;
    const float* dep  = depth + (size_t)b * 65536;

    if (tid >= 256) {
        // ---------------- producer: 4 waves ----------------
        const int ptid = tid - 256;
        const int cgp  = ptid & 15;          // 4-channel group

        // P(0): local rows 0..3 -> slots 0..3 (1088 units of 4ch x 4col)
#pragma unroll
        for (int k = 0; k < 5; ++k) {
            const int u = ptid + (k << 8);
            if (u < 1088) {
                const int rest = u >> 4;
                const int colg = rest % 17, row = rest / 17;
                const float* src = imgb + (size_t)(cgp * 4) * 65536
                                 + (size_t)(prow0 + row) * 256 + s0 + colg * 4;
                const f32x4 v0 = *(const f32x4*)src;
                const f32x4 v1 = *(const f32x4*)(src + 65536);
                const f32x4 v2 = *(const f32x4*)(src + 2 * 65536);
                const f32x4 v3 = *(const f32x4*)(src + 3 * 65536);
                bf16_t* dst = lds + (size_t)(row * NCOL + colg * 4) * CPAD + cgp * 4;
#pragma unroll
                for (int i = 0; i < 4; ++i)
                    *(bf16x4*)(dst + i * CPAD) =
                        (bf16x4){(bf16_t)v0[i], (bf16_t)v1[i], (bf16_t)v2[i], (bf16_t)v3[i]};
            }
        }
        asm volatile("s_waitcnt lgkmcnt(0)" ::: "memory");
        __builtin_amdgcn_s_barrier();                    // bar 1: tile 0 ready

        // P(s): stage local rows 2s+2, 2s+3 while consumers compute tile s-1
#pragma unroll 1
        for (int s = 1; s < 4; ++s) {
            const int lb = 2 * s + 2;
#pragma unroll
            for (int k = 0; k < 3; ++k) {
                const int u = ptid + (k << 8);
                if (u < 544) {
                    const int rest = u >> 4;
                    const int colg = rest % 17, row = rest / 17;   // row 0..1
                    const int l    = lb + row;
                    const int slot = (l >= NSLOT) ? l - NSLOT : l;
                    const float* src = imgb + (size_t)(cgp * 4) * 65536
                                     + (size_t)(prow0 + l) * 256 + s0 + colg * 4;
                    const f32x4 v0 = *(const f32x4*)src;
                    const f32x4 v1 = *(const f32x4*)(src + 65536);
                    const f32x4 v2 = *(const f32x4*)(src + 2 * 65536);
                    const f32x4 v3 = *(const f32x4*)(src + 3 * 65536);
                    bf16_t* dst = lds + (size_t)(slot * NCOL + colg * 4) * CPAD + cgp * 4;
#pragma unroll
                    for (int i = 0; i < 4; ++i)
                        *(bf16x4*)(dst + i * CPAD) =
                            (bf16x4){(bf16_t)v0[i], (bf16_t)v1[i], (bf16_t)v2[i], (bf16_t)v3[i]};
                }
            }
            asm volatile("s_waitcnt lgkmcnt(0)" ::: "memory");
            __builtin_amdgcn_s_barrier();                // bar s+1: tile s ready
        }
    } else {
        // ---------------- consumer: 4 waves = (2 p-rows) x (2 oc-halves) ----------------
        const int wv   = tid >> 6;
        const int lane = tid & 63;
        const int pr   = wv >> 1;
        const int mh   = wv & 1;
        const int n    = lane & 15;
        const int quad = lane >> 4;

        const bf16x8* wbase = (const bf16x8*)w2 + (size_t)(mh * 2) * 64 + lane;
        const f32x4 Z = (f32x4){0.f, 0.f, 0.f, 0.f};

        __builtin_amdgcn_s_barrier();                    // bar 1: wait for tile 0

#pragma unroll 1
        for (int s = 0; s < 4; ++s) {
            const int prow = prow0 + 2 * s + pr;

            float dc[4];
#pragma unroll
            for (int i = 0; i < 4; ++i)
                dc[i] = dep[(size_t)(prow + 1) * 256 + q0 + 16 * i + n + 1];

            f32x4 acc[2][4];
#pragma unroll
            for (int mm = 0; mm < 2; ++mm)
#pragma unroll
                for (int i = 0; i < 4; ++i) acc[mm][i] = Z;

#pragma unroll
            for (int kt = 0; kt < 3; ++kt) {
                const int l    = 2 * s + pr + kt;        // local row 0..9
                const int slot = (l >= NSLOT) ? l - NSLOT : l;
                float dwv[3][4];
#pragma unroll
                for (int lt = 0; lt < 3; ++lt)
#pragma unroll
                    for (int i = 0; i < 4; ++i) {
                        float d = dep[(size_t)(prow + kt) * 256 + q0 + 16 * i + n + lt];
                        dwv[lt][i] = __expf(-ALPHA * fabsf(d - dc[i]));
                    }
#pragma unroll
                for (int lt = 0; lt < 3; ++lt) {
                    const int tap = kt * 3 + lt;
                    const bf16x8* w2p = wbase + (size_t)tap * 512;
                    const bf16x8 a00 = w2p[0];           // chunk0, mm0
                    const bf16x8 a01 = w2p[64];          // chunk0, mm1
                    const bf16x8 a10 = w2p[256];         // chunk1, mm0
                    const bf16x8 a11 = w2p[320];         // chunk1, mm1
#pragma unroll
                    for (int i = 0; i < 4; ++i) {
                        const bf16_t* lp = lds
                            + (size_t)(slot * NCOL + clb0 + 16 * i + n + lt) * CPAD + quad * 8;
                        const bf16x8 bf0 = *(const bf16x8*)lp;
                        const bf16x8 bf1 = *(const bf16x8*)(lp + 32);
                        f32x4 P0 = __builtin_amdgcn_mfma_f32_16x16x32_bf16(a00, bf0, Z, 0, 0, 0);
                        f32x4 P1 = __builtin_amdgcn_mfma_f32_16x16x32_bf16(a01, bf0, Z, 0, 0, 0);
                        P0 = __builtin_amdgcn_mfma_f32_16x16x32_bf16(a10, bf1, P0, 0, 0, 0);
                        P1 = __builtin_amdgcn_mfma_f32_16x16x32_bf16(a11, bf1, P1, 0, 0, 0);
                        acc[0][i] += dwv[lt][i] * P0;
                        acc[1][i] += dwv[lt][i] * P1;
                    }
                }
            }

            // epilogue: D[row=quad*4+r2][col=n]; oc = (mh*2+mm)*16 + quad*4 + r2
#pragma unroll
            for (int mm = 0; mm < 2; ++mm)
#pragma unroll
                for (int r2 = 0; r2 < 4; ++r2) {
                    const int oc = (mh * 2 + mm) * 16 + quad * 4 + r2;
                    const float bz = bias[oc];
#pragma unroll
                    for (int i = 0; i < 4; ++i)
                        out[((size_t)(b * 64 + oc) * 254 + prow) * 254 + q0 + 16 * i + n]
                            = acc[mm][i][r2] + bz;
                }

            if (s < 3) {
                asm volatile("s_waitcnt lgkmcnt(0)" ::: "memory");
                __builtin_amdgcn_s_barrier();            // bar s+2: next tile ready
            }
        }
    }
}

extern "C" void kernel_launch(void* const* d_in, const int* in_sizes, int n_in,
                              void* d_out, int out_size, void* d_ws, size_t ws_size,
                              hipStream_t stream) {
    const float* img   = (const float*)d_in[0];
    const float* depth = (const float*)d_in[1];
    const float* w     = (const float*)d_in[2];
    const float* bias  = (const float*)d_in[3];
    bf16_t* w2 = (bf16_t*)d_ws;

    repack_w<<<144, 256, 0, stream>>>(w, w2);
    // 32 strips x 4 b x 4 q-tiles = 512 blocks, 512 thr (4 producer + 4 consumer waves)
    depthconv_mfma<<<512, 512, 0, stream>>>(img, depth, w2, bias, (float*)d_out);
}

// Round 7
// 175.210 us; speedup vs baseline: 1.2756x; 1.2507x over previous
//
#include <hip/hip_runtime.h>
#include <hip/hip_bf16.h>

typedef __bf16 bf16_t;
typedef __bf16 bf16x4 __attribute__((ext_vector_type(4)));
typedef __bf16 bf16x8 __attribute__((ext_vector_type(8)));
typedef float f32x4 __attribute__((ext_vector_type(4)));

#define ALPHA 8.3f
#define CPAD 72   // bf16 channel stride (144 B, 16B-aligned, conflict-free reads)
#define NCOL 68   // staged cols (64-q tile + halo + align)
#define NSLOT 6   // LDS row-ring slots

// img: [4][64][256][256] f32, depth: [4][1][256][256] f32,
// weight: [64][64][3][3] f32, bias: [1][64] f32, out: [4][64][254][254] f32

// Repack weight -> bf16 A-fragment order [tap(9)][chunk(2)][mblock(4)][lane(64)][j(8)]
__global__ void repack_w(const float* __restrict__ w, bf16_t* __restrict__ w2) {
    int idx = blockIdx.x * 256 + threadIdx.x;  // 0..36863
    if (idx >= 9 * 2 * 4 * 64 * 8) return;
    int j     = idx & 7;
    int lane  = (idx >> 3) & 63;
    int m     = (idx >> 9) & 3;
    int chunk = (idx >> 11) & 1;
    int tap   = idx >> 12;
    int oc = m * 16 + (lane & 15);
    int c  = chunk * 32 + (lane >> 4) * 8 + j;
    int kt = tap / 3, lt = tap % 3;
    w2[idx] = (bf16_t)w[((oc * 64 + c) * 3 + kt) * 3 + lt];
}

// R6 post-mortem: __launch_bounds__(512,4) -> compiler targeted 8 waves/EU ->
// 64-VGPR cap; consumer live set ~90+ SPILLED (FETCH 219/WRITE 180, both
// +~110MB of scratch round-trips -- same signature as R4's 162/179). The P/C
// overlap itself WORKED: hbm duty 3.1 TB/s, highest measured. R7: identical
// kernel, launch_bounds (512,2) (cap 256). Natural alloc ~100-120 VGPR -> HW
// still gives 4 waves/EU -> LDS (58.8KB) keeps 2 blocks/CU. Spills gone.
// Structure: 512 thr = 4 producer waves (stage img->LDS bf16 ring) + 4
// consumer waves (MFMA from ring). 6-row LDS ring over a 4-tile strip
// (8 output rows); P(s) stages rows 2s+2,2s+3 while C computes tile s-1.
// Raw lgkm-only barriers keep producer global loads in flight across epochs.
// Ring math: P writes {2s+2,2s+3}%6 vs C reads {2s-2..2s+1}%6 -- 6 consecutive
// rows, distinct mod 6 -> race-free. Barrier counts: both paths hit exactly 4.
__global__ __launch_bounds__(512, 2) void depthconv_mfma(
    const float* __restrict__ img, const float* __restrict__ depth,
    const bf16_t* __restrict__ w2, const float* __restrict__ bias,
    float* __restrict__ out)
{
    __shared__ bf16_t lds[NSLOT * NCOL * CPAD];  // 58,752 B -> 2 blocks/CU

    const int tid   = threadIdx.x;
    const int blk   = blockIdx.x;
    const int strip = blk >> 4;              // 0..31, 4 tiles (8 output rows) each
    const int r     = blk & 15;              // (b,qt) stream; 16%8==0 -> XCD-stable
    const int b     = r >> 2;
    const int qt    = r & 3;
    // strip 31 overlaps strip 30 (ppair 123) -> identical dup writes
    const int prow0 = ((strip == 31) ? 123 : strip * 4) * 2;
    const int q0    = (qt == 3) ? 190 : qt * 64;   // q 190/191 dup-written identically
    const int s0    = (qt == 3) ? 188 : q0;        // staged col start (float4-aligned)
    const int clb0  = q0 - s0;

    const float* imgb = img + (size_t)b * 64 * 65536;
    const float* dep  = depth + (size_t)b * 65536;

    if (tid >= 256) {
        // ---------------- producer: 4 waves ----------------
        const int ptid = tid - 256;
        const int cgp  = ptid & 15;          // 4-channel group

        // P(0): local rows 0..3 -> slots 0..3 (1088 units of 4ch x 4col)
#pragma unroll
        for (int k = 0; k < 5; ++k) {
            const int u = ptid + (k << 8);
            if (u < 1088) {
                const int rest = u >> 4;
                const int colg = rest % 17, row = rest / 17;
                const float* src = imgb + (size_t)(cgp * 4) * 65536
                                 + (size_t)(prow0 + row) * 256 + s0 + colg * 4;
                const f32x4 v0 = *(const f32x4*)src;
                const f32x4 v1 = *(const f32x4*)(src + 65536);
                const f32x4 v2 = *(const f32x4*)(src + 2 * 65536);
                const f32x4 v3 = *(const f32x4*)(src + 3 * 65536);
                bf16_t* dst = lds + (size_t)(row * NCOL + colg * 4) * CPAD + cgp * 4;
#pragma unroll
                for (int i = 0; i < 4; ++i)
                    *(bf16x4*)(dst + i * CPAD) =
                        (bf16x4){(bf16_t)v0[i], (bf16_t)v1[i], (bf16_t)v2[i], (bf16_t)v3[i]};
            }
        }
        asm volatile("s_waitcnt lgkmcnt(0)" ::: "memory");
        __builtin_amdgcn_s_barrier();                    // bar 1: tile 0 ready

        // P(s): stage local rows 2s+2, 2s+3 while consumers compute tile s-1
#pragma unroll 1
        for (int s = 1; s < 4; ++s) {
            const int lb = 2 * s + 2;
#pragma unroll
            for (int k = 0; k < 3; ++k) {
                const int u = ptid + (k << 8);
                if (u < 544) {
                    const int rest = u >> 4;
                    const int colg = rest % 17, row = rest / 17;   // row 0..1
                    const int l    = lb + row;
                    const int slot = (l >= NSLOT) ? l - NSLOT : l;
                    const float* src = imgb + (size_t)(cgp * 4) * 65536
                                     + (size_t)(prow0 + l) * 256 + s0 + colg * 4;
                    const f32x4 v0 = *(const f32x4*)src;
                    const f32x4 v1 = *(const f32x4*)(src + 65536);
                    const f32x4 v2 = *(const f32x4*)(src + 2 * 65536);
                    const f32x4 v3 = *(const f32x4*)(src + 3 * 65536);
                    bf16_t* dst = lds + (size_t)(slot * NCOL + colg * 4) * CPAD + cgp * 4;
#pragma unroll
                    for (int i = 0; i < 4; ++i)
                        *(bf16x4*)(dst + i * CPAD) =
                            (bf16x4){(bf16_t)v0[i], (bf16_t)v1[i], (bf16_t)v2[i], (bf16_t)v3[i]};
                }
            }
            asm volatile("s_waitcnt lgkmcnt(0)" ::: "memory");
            __builtin_amdgcn_s_barrier();                // bar s+1: tile s ready
        }
    } else {
        // ---------------- consumer: 4 waves = (2 p-rows) x (2 oc-halves) ----------------
        const int wv   = tid >> 6;
        const int lane = tid & 63;
        const int pr   = wv >> 1;
        const int mh   = wv & 1;
        const int n    = lane & 15;
        const int quad = lane >> 4;

        const bf16x8* wbase = (const bf16x8*)w2 + (size_t)(mh * 2) * 64 + lane;
        const f32x4 Z = (f32x4){0.f, 0.f, 0.f, 0.f};

        __builtin_amdgcn_s_barrier();                    // bar 1: wait for tile 0

#pragma unroll 1
        for (int s = 0; s < 4; ++s) {
            const int prow = prow0 + 2 * s + pr;

            float dc[4];
#pragma unroll
            for (int i = 0; i < 4; ++i)
                dc[i] = dep[(size_t)(prow + 1) * 256 + q0 + 16 * i + n + 1];

            f32x4 acc[2][4];
#pragma unroll
            for (int mm = 0; mm < 2; ++mm)
#pragma unroll
                for (int i = 0; i < 4; ++i) acc[mm][i] = Z;

#pragma unroll
            for (int kt = 0; kt < 3; ++kt) {
                const int l    = 2 * s + pr + kt;        // local row 0..9
                const int slot = (l >= NSLOT) ? l - NSLOT : l;
                float dwv[3][4];
#pragma unroll
                for (int lt = 0; lt < 3; ++lt)
#pragma unroll
                    for (int i = 0; i < 4; ++i) {
                        float d = dep[(size_t)(prow + kt) * 256 + q0 + 16 * i + n + lt];
                        dwv[lt][i] = __expf(-ALPHA * fabsf(d - dc[i]));
                    }
#pragma unroll
                for (int lt = 0; lt < 3; ++lt) {
                    const int tap = kt * 3 + lt;
                    const bf16x8* w2p = wbase + (size_t)tap * 512;
                    const bf16x8 a00 = w2p[0];           // chunk0, mm0
                    const bf16x8 a01 = w2p[64];          // chunk0, mm1
                    const bf16x8 a10 = w2p[256];         // chunk1, mm0
                    const bf16x8 a11 = w2p[320];         // chunk1, mm1
#pragma unroll
                    for (int i = 0; i < 4; ++i) {
                        const bf16_t* lp = lds
                            + (size_t)(slot * NCOL + clb0 + 16 * i + n + lt) * CPAD + quad * 8;
                        const bf16x8 bf0 = *(const bf16x8*)lp;
                        const bf16x8 bf1 = *(const bf16x8*)(lp + 32);
                        f32x4 P0 = __builtin_amdgcn_mfma_f32_16x16x32_bf16(a00, bf0, Z, 0, 0, 0);
                        f32x4 P1 = __builtin_amdgcn_mfma_f32_16x16x32_bf16(a01, bf0, Z, 0, 0, 0);
                        P0 = __builtin_amdgcn_mfma_f32_16x16x32_bf16(a10, bf1, P0, 0, 0, 0);
                        P1 = __builtin_amdgcn_mfma_f32_16x16x32_bf16(a11, bf1, P1, 0, 0, 0);
                        acc[0][i] += dwv[lt][i] * P0;
                        acc[1][i] += dwv[lt][i] * P1;
                    }
                }
            }

            // epilogue: D[row=quad*4+r2][col=n]; oc = (mh*2+mm)*16 + quad*4 + r2
#pragma unroll
            for (int mm = 0; mm < 2; ++mm)
#pragma unroll
                for (int r2 = 0; r2 < 4; ++r2) {
                    const int oc = (mh * 2 + mm) * 16 + quad * 4 + r2;
                    const float bz = bias[oc];
#pragma unroll
                    for (int i = 0; i < 4; ++i)
                        out[((size_t)(b * 64 + oc) * 254 + prow) * 254 + q0 + 16 * i + n]
                            = acc[mm][i][r2] + bz;
                }

            if (s < 3) {
                asm volatile("s_waitcnt lgkmcnt(0)" ::: "memory");
                __builtin_amdgcn_s_barrier();            // bar s+2: next tile ready
            }
        }
    }
}

extern "C" void kernel_launch(void* const* d_in, const int* in_sizes, int n_in,
                              void* d_out, int out_size, void* d_ws, size_t ws_size,
                              hipStream_t stream) {
    const float* img   = (const float*)d_in[0];
    const float* depth = (const float*)d_in[1];
    const float* w     = (const float*)d_in[2];
    const float* bias  = (const float*)d_in[3];
    bf16_t* w2 = (bf16_t*)d_ws;

    repack_w<<<144, 256, 0, stream>>>(w, w2);
    // 32 strips x 4 b x 4 q-tiles = 512 blocks, 512 thr (4 producer + 4 consumer waves)
    depthconv_mfma<<<512, 512, 0, stream>>>(img, depth, w2, bias, (float*)d_out);
}